// Round 8
// baseline (209.008 us; speedup 1.0000x reference)
//
#include <hip/hip_runtime.h>
#include <hip/hip_bf16.h>

// Problem constants (B=4, T=4096, C=1024, H=128)
#define T_SEQ 4096
#define NBATCH 4
#define C_EMB 1024
#define H_DIM 128
#define M_ROWS (NBATCH * T_SEQ)   // 16384
#define SPLIT 4                   // j-chunks per Q-tile (flash split-K)

typedef __bf16 bf16x8 __attribute__((ext_vector_type(8)));
typedef float  floatx4 __attribute__((ext_vector_type(4)));

__device__ __forceinline__ ushort f2bf(float f) {
    __hip_bfloat16 h = __float2bfloat16(f);
    return *reinterpret_cast<ushort*>(&h);
}
__device__ __forceinline__ float bf2f(ushort u) {
    unsigned int v = ((unsigned int)u) << 16;
    return *reinterpret_cast<float*>(&v);
}
__device__ __forceinline__ uint4 pack8(const float4& a, const float4& b) {
    __hip_bfloat162 h0 = __float22bfloat162_rn(make_float2(a.x, a.y));
    __hip_bfloat162 h1 = __float22bfloat162_rn(make_float2(a.z, a.w));
    __hip_bfloat162 h2 = __float22bfloat162_rn(make_float2(b.x, b.y));
    __hip_bfloat162 h3 = __float22bfloat162_rn(make_float2(b.z, b.w));
    uint4 r;
    r.x = *reinterpret_cast<unsigned int*>(&h0);
    r.y = *reinterpret_cast<unsigned int*>(&h1);
    r.z = *reinterpret_cast<unsigned int*>(&h2);
    r.w = *reinterpret_cast<unsigned int*>(&h3);
    return r;
}
// Async global->LDS, 16 B/lane. LDS dst is wave-uniform base + lane*16.
__device__ __forceinline__ void gld16(const ushort* g, ushort* l) {
    __builtin_amdgcn_global_load_lds(
        (const __attribute__((address_space(1))) unsigned int*)(g),
        (__attribute__((address_space(3))) unsigned int*)(l),
        16, 0, 0);
}

// ---------------------------------------------------------------------------
// Kernel 0: transpose weights fp32 [C][H] -> bf16 Wt[z][H][K=C].
// ---------------------------------------------------------------------------
__global__ __launch_bounds__(256) void transpose_w(
    const float* __restrict__ Wk, const float* __restrict__ Wq,
    const float* __restrict__ Wv, ushort* __restrict__ wt) {
    const int z = blockIdx.y;
    const float* W = (z == 0) ? Wk : (z == 1) ? Wq : Wv;
    ushort* Wtz = wt + (size_t)z * H_DIM * C_EMB;
    int linear = blockIdx.x * 256 + threadIdx.x;       // [0, 16384)
    int n  = linear >> 7;                              // 0..127
    int k0 = (linear & 127) << 3;                      // 0..1016 step 8
    ushort tmp[8];
#pragma unroll
    for (int j = 0; j < 8; ++j)
        tmp[j] = f2bf(W[(size_t)(k0 + j) * H_DIM + n]);
    uint4 pk;
    pk.x = (unsigned int)tmp[0] | ((unsigned int)tmp[1] << 16);
    pk.y = (unsigned int)tmp[2] | ((unsigned int)tmp[3] << 16);
    pk.z = (unsigned int)tmp[4] | ((unsigned int)tmp[5] << 16);
    pk.w = (unsigned int)tmp[6] | ((unsigned int)tmp[7] << 16);
    *reinterpret_cast<uint4*>(Wtz + (size_t)n * C_EMB + k0) = pk;
}

// ---------------------------------------------------------------------------
// Kernel 1: fused QKV GEMM, 128m x 192n tile, dbuf 2-phase staging.
// grid (128, 2) x 512 threads (8 waves, each 16m x 192n, 24 MFMA/kt).
// LDS: As 2x16 KB + Bs 2x24 KB = 80 KB -> 2 blocks/CU = 16 waves/CU
// (4 waves/SIMD, 2x the 64x384 version's occupancy). n-half cb = 0 or 192;
// x read twice total (L3-served). One barrier per kt; B via gld16 issued
// before compute (latency hidden under MFMA). Plain-local x prefetch regs.
// ---------------------------------------------------------------------------
__global__ __launch_bounds__(512, 4) void qkv_gemm(
    const float* __restrict__ x, const ushort* __restrict__ wt,
    ushort* __restrict__ kqv) {
    const int m0 = blockIdx.x * 128;
    const int cb = blockIdx.y * 192;

    __shared__ ushort As[2][128 * 64];    // 2 x 16 KB
    __shared__ ushort Bs[2][192 * 64];    // 2 x 24 KB

    const int tid  = threadIdx.x;
    const int lane = tid & 63;
    const int wave = tid >> 6;          // 0..7
    const int l15  = lane & 15;
    const int quad = lane >> 4;
    const int mg   = wave * 16;         // m sub-block

    floatx4 acc[12];
#pragma unroll
    for (int nj = 0; nj < 12; ++nj) acc[nj] = floatx4{0.f, 0.f, 0.f, 0.f};

    // A-path: thread covers rows ar and ar+64, chunk ac (8 floats each)
    const int ar = tid >> 3;            // 0..63
    const int ac = tid & 7;             // 0..7
    const int chp = ac ^ (ar & 7);      // (ar+64)&7 == ar&7 -> same swizzle
    const float* xr0 = x + (size_t)(m0 + ar) * C_EMB + ac * 8;
    const float* xr1 = xr0 + (size_t)64 * C_EMB;

    // ---- prologue: stage kt=0 into buffer 0 ----
    float4 xa0 = *reinterpret_cast<const float4*>(xr0);
    float4 xb0 = *reinterpret_cast<const float4*>(xr0 + 4);
    float4 xa1 = *reinterpret_cast<const float4*>(xr1);
    float4 xb1 = *reinterpret_cast<const float4*>(xr1 + 4);
#pragma unroll
    for (int i = 0; i < 3; ++i) {
        int rbase = wave * 24 + i * 8;
        int row = rbase + (lane >> 3);
        int chg = (lane & 7) ^ (row & 7);
        gld16(wt + (size_t)(cb + row) * C_EMB + chg * 8, Bs[0] + rbase * 64);
    }
    *reinterpret_cast<uint4*>(As[0] + ar * 64 + chp * 8)        = pack8(xa0, xb0);
    *reinterpret_cast<uint4*>(As[0] + (ar + 64) * 64 + chp * 8) = pack8(xa1, xb1);
    __syncthreads();   // buffer 0 ready
    // x regs for kt=1
    xa0 = *reinterpret_cast<const float4*>(xr0 + 64);
    xb0 = *reinterpret_cast<const float4*>(xr0 + 68);
    xa1 = *reinterpret_cast<const float4*>(xr1 + 64);
    xb1 = *reinterpret_cast<const float4*>(xr1 + 68);

    for (int kt = 0; kt < 16; ++kt) {
        const int cur = kt & 1;

        // ---- stage kt+1 into the other buffer (async; lands by next barrier)
        if (kt < 15) {
#pragma unroll
            for (int i = 0; i < 3; ++i) {
                int rbase = wave * 24 + i * 8;
                int row = rbase + (lane >> 3);
                int chg = (lane & 7) ^ (row & 7);
                gld16(wt + (size_t)(cb + row) * C_EMB + (kt + 1) * 64 + chg * 8,
                      Bs[cur ^ 1] + rbase * 64);
            }
            *reinterpret_cast<uint4*>(As[cur ^ 1] + ar * 64 + chp * 8)        = pack8(xa0, xb0);
            *reinterpret_cast<uint4*>(As[cur ^ 1] + (ar + 64) * 64 + chp * 8) = pack8(xa1, xb1);
        }
        // issue x loads for kt+2 (latency hides under this kt's MFMA phase)
        if (kt < 14) {
            const float* n0 = xr0 + (kt + 2) * 64;
            const float* n1 = xr1 + (kt + 2) * 64;
            xa0 = *reinterpret_cast<const float4*>(n0);
            xb0 = *reinterpret_cast<const float4*>(n0 + 4);
            xa1 = *reinterpret_cast<const float4*>(n1);
            xb1 = *reinterpret_cast<const float4*>(n1 + 4);
        }

        // ---- compute on buffer cur ----
#pragma unroll
        for (int kk = 0; kk < 2; ++kk) {
            bf16x8 a = *reinterpret_cast<const bf16x8*>(
                As[cur] + (mg + l15) * 64 + ((4 * kk + quad) ^ (l15 & 7)) * 8);
#pragma unroll
            for (int nj = 0; nj < 12; ++nj) {
                int brow = nj * 16 + l15;          // brow&7 == l15&7
                bf16x8 b = *reinterpret_cast<const bf16x8*>(
                    Bs[cur] + brow * 64 + ((4 * kk + quad) ^ (l15 & 7)) * 8);
                acc[nj] = __builtin_amdgcn_mfma_f32_16x16x32_bf16(a, b, acc[nj], 0, 0, 0);
            }
        }

        __syncthreads();   // drains next tile's gld16 + ds_writes; reads done
    }

    // epilogue: z = gcol>>7 is uniform per nj (16-col blocks never straddle)
    const int rowb = m0 + mg + quad * 4;
#pragma unroll
    for (int nj = 0; nj < 12; ++nj) {
        int gcol = cb + nj * 16 + l15;
        int z = gcol >> 7;
        int cz = gcol & 127;
        if (z < 2) {
            const float scale = (z == 0) ? 0.03125f : 1.0f;   // fold C^-0.5 into k
            ushort* outz = kqv + (size_t)z * M_ROWS * H_DIM;
#pragma unroll
            for (int r = 0; r < 4; ++r)
                outz[(size_t)(rowb + r) * H_DIM + cz] = f2bf(acc[nj][r] * scale);
        } else {
            ushort* vt = kqv + (size_t)2 * M_ROWS * H_DIM;
            int bb   = rowb >> 12;
            int tloc = rowb & (T_SEQ - 1);
            ushort4 pk;
            pk.x = f2bf(acc[nj][0]);
            pk.y = f2bf(acc[nj][1]);
            pk.z = f2bf(acc[nj][2]);
            pk.w = f2bf(acc[nj][3]);
            *reinterpret_cast<ushort4*>(
                vt + ((size_t)(bb * H_DIM + cz) << 12) + tloc) = pk;
        }
    }
}

// ---------------------------------------------------------------------------
// Kernel 2: flash attention chunks (split-K). R3 structure (62 us) with the
// Ps pad replaced by a chunk-XOR swizzle: P_STRIDE 72 -> 64, LDS 41984 ->
// 40960 B -> 4 blocks/CU (16 waves/CU, +33% cross-block TLP — the only
// knob with a consistently positive signal: R2->R3 2->3 blk was -12 us).
// Single-buffer, two barriers per j-tile (dbuf and shared-tile variants
// both regressed: R1 71.5, R7 66.4). grid (64*SPLIT, 4) x 256 threads.
// ---------------------------------------------------------------------------
__global__ __launch_bounds__(256, 4) void flash_chunk(
    const ushort* __restrict__ kqv, ushort* __restrict__ partO,
    float* __restrict__ partML) {
    const int it = blockIdx.x >> 2;
    const int c  = blockIdx.x & 3;
    if (c > it) return;                 // block-uniform early out
    const int b  = blockIdx.y;
    const int i0 = it * 64;

    const ushort* Qg = kqv + (size_t)b * T_SEQ * H_DIM;                          // k proj (query role)
    const ushort* Kg = kqv + (size_t)M_ROWS * H_DIM + (size_t)b * T_SEQ * H_DIM; // q proj (key role)
    const ushort* Vt = kqv + (size_t)2 * M_ROWS * H_DIM + (size_t)b * H_DIM * T_SEQ; // vT[h][t]

    __shared__ ushort Ks[64 * 128];      // 16 KB, row = 128 u (16 chunks)
    __shared__ ushort Vs[128 * 64];      // 16 KB, row = 64 u (8 chunks)
    __shared__ ushort Ps[4][16 * 64];    // 8 KB, chunk-XOR swizzled (no pad)

    const int tid  = threadIdx.x;
    const int lane = tid & 63;
    const int wave = tid >> 6;
    const int l15  = lane & 15;
    const int quad = lane >> 4;

    // Q fragments: row = i0 + wave*16 + l15, k = kk*32 + quad*8
    bf16x8 q[4];
    {
        const ushort* qrow = Qg + (size_t)(i0 + wave * 16 + l15) * H_DIM + quad * 8;
#pragma unroll
        for (int kk = 0; kk < 4; ++kk)
            q[kk] = *reinterpret_cast<const bf16x8*>(qrow + kk * 32);
    }

    float m_i[4], l_i[4];
#pragma unroll
    for (int r = 0; r < 4; ++r) { m_i[r] = -1e30f; l_i[r] = 0.f; }
    floatx4 o[8];
#pragma unroll
    for (int nh = 0; nh < 8; ++nh) o[nh] = floatx4{0.f, 0.f, 0.f, 0.f};

    ushort* Pw = Ps[wave];

    for (int jt = c; jt <= it; jt += SPLIT) {
        const int j0 = jt * 64;
        __syncthreads();   // previous tile's LDS reads done
        // K: 64 rows x 128 u; wave w instr i covers rows w*16+i*4..+3
#pragma unroll
        for (int i = 0; i < 4; ++i) {
            int row = wave * 16 + i * 4 + (lane >> 4);
            int chg = (lane & 15) ^ (row & 15);
            gld16(Kg + (size_t)(j0 + row) * H_DIM + chg * 8,
                  Ks + (wave * 16 + i * 4) * 128);
        }
        // V: 128 rows x 64 u; wave w instr i covers rows w*32+i*8..+7
#pragma unroll
        for (int i = 0; i < 4; ++i) {
            int row = wave * 32 + i * 8 + (lane >> 3);
            int chg = (lane & 7) ^ (row & 7);
            gld16(Vt + (size_t)row * T_SEQ + j0 + chg * 8,
                  Vs + (wave * 32 + i * 8) * 64);
        }
        __syncthreads();   // drains vmcnt -> tiles landed

        // S = Q K^T (wave's 16 rows x 64 cols), K-dim = H = 128
        floatx4 s[4];
#pragma unroll
        for (int ni = 0; ni < 4; ++ni) s[ni] = floatx4{0.f, 0.f, 0.f, 0.f};
#pragma unroll
        for (int kk = 0; kk < 4; ++kk)
#pragma unroll
            for (int ni = 0; ni < 4; ++ni) {
                bf16x8 kb = *reinterpret_cast<const bf16x8*>(
                    Ks + (ni * 16 + l15) * 128 + ((4 * kk + quad) ^ l15) * 8);
                s[ni] = __builtin_amdgcn_mfma_f32_16x16x32_bf16(q[kk], kb, s[ni], 0, 0, 0);
            }

        if (jt == it) {   // causal mask, diagonal tile only
            int ii = i0 + wave * 16 + quad * 4;
#pragma unroll
            for (int ni = 0; ni < 4; ++ni) {
                int j = j0 + ni * 16 + l15;
#pragma unroll
                for (int r = 0; r < 4; ++r)
                    if (j > ii + r) s[ni][r] = -1e30f;
            }
        }

        // online softmax (rows = quad*4 + r; reduce across 16 l15 lanes)
        float alpha[4], rs[4];
#pragma unroll
        for (int r = 0; r < 4; ++r) {
            float v = fmaxf(fmaxf(s[0][r], s[1][r]), fmaxf(s[2][r], s[3][r]));
#pragma unroll
            for (int off = 8; off >= 1; off >>= 1)
                v = fmaxf(v, __shfl_xor(v, off, 64));
            float mn = fmaxf(m_i[r], v);
            alpha[r] = __expf(m_i[r] - mn);
            m_i[r] = mn;
            rs[r] = 0.f;
        }
#pragma unroll
        for (int ni = 0; ni < 4; ++ni)
#pragma unroll
            for (int r = 0; r < 4; ++r) {
                float p = __expf(s[ni][r] - m_i[r]);
                rs[r] += p;
                int prow = quad * 4 + r;
                int pc8  = (ni * 2 + (l15 >> 3)) ^ (prow & 7);
                Pw[prow * 64 + pc8 * 8 + (l15 & 7)] = f2bf(p);
            }
#pragma unroll
        for (int r = 0; r < 4; ++r) {
            float v = rs[r];
#pragma unroll
            for (int off = 8; off >= 1; off >>= 1)
                v += __shfl_xor(v, off, 64);
            l_i[r] = l_i[r] * alpha[r] + v;
        }
#pragma unroll
        for (int nh = 0; nh < 8; ++nh)
#pragma unroll
            for (int r = 0; r < 4; ++r) o[nh][r] *= alpha[r];

        // O += P V : A-frag from per-wave swizzled Ps (row l15, chunk
        // (kp*4+quad)^(l15&7) inverts the write swizzle), B-frag from Vs.
#pragma unroll
        for (int kp = 0; kp < 2; ++kp) {
            bf16x8 a = *reinterpret_cast<const bf16x8*>(
                Pw + l15 * 64 + ((kp * 4 + quad) ^ (l15 & 7)) * 8);
#pragma unroll
            for (int nh = 0; nh < 8; ++nh) {
                bf16x8 vb = *reinterpret_cast<const bf16x8*>(
                    Vs + (nh * 16 + l15) * 64 + ((4 * kp + quad) ^ (l15 & 7)) * 8);
                o[nh] = __builtin_amdgcn_mfma_f32_16x16x32_bf16(a, vb, o[nh], 0, 0, 0);
            }
        }
    }

    // write partials: O' (bf16, unnormalized) + m, l (fp32)
    const int idx = ((b * 64 + it) << 2) + c;
    ushort* po = partO + (size_t)idx * 64 * 128;
#pragma unroll
    for (int nh = 0; nh < 8; ++nh)
#pragma unroll
        for (int r = 0; r < 4; ++r) {
            int row = wave * 16 + quad * 4 + r;
            po[(size_t)row * 128 + nh * 16 + l15] = f2bf(o[nh][r]);
        }
    if (l15 == 0) {
        float* ml = partML + (size_t)idx * 128;
#pragma unroll
        for (int r = 0; r < 4; ++r) {
            int row = wave * 16 + quad * 4 + r;
            ml[row]      = m_i[r];
            ml[64 + row] = l_i[r];
        }
    }
}

// ---------------------------------------------------------------------------
// Kernel 3: combine partials. grid (64, 4) x 256 threads.
// ---------------------------------------------------------------------------
__global__ __launch_bounds__(256) void combine(
    const ushort* __restrict__ partO, const float* __restrict__ partML,
    float* __restrict__ out) {
    const int it = blockIdx.x, b = blockIdx.y;
    const int count = min(SPLIT, it + 1);
    const int tid = threadIdx.x;
    const int row = tid >> 2;
    const int cg  = (tid & 3) * 32;
    const int base = (b * 64 + it) << 2;

    float m_c[SPLIT], l_c[SPLIT];
    float M = -1e30f;
    for (int cc = 0; cc < count; ++cc) {
        const float* ml = partML + (size_t)(base + cc) * 128;
        m_c[cc] = ml[row];
        l_c[cc] = ml[64 + row];
        M = fmaxf(M, m_c[cc]);
    }
    float L = 0.f, w[SPLIT];
    for (int cc = 0; cc < count; ++cc) {
        w[cc] = __expf(m_c[cc] - M);
        L += w[cc] * l_c[cc];
    }

    float acc[32];
#pragma unroll
    for (int j = 0; j < 32; ++j) acc[j] = 0.f;
    for (int cc = 0; cc < count; ++cc) {
        const ushort* po = partO + (size_t)(base + cc) * 8192 + (size_t)row * 128 + cg;
        float wc = w[cc];
#pragma unroll
        for (int g = 0; g < 4; ++g) {
            uint4 v = *reinterpret_cast<const uint4*>(po + g * 8);
            const ushort* pv = reinterpret_cast<const ushort*>(&v);
#pragma unroll
            for (int e = 0; e < 8; ++e)
                acc[g * 8 + e] += wc * bf2f(pv[e]);
        }
    }
    float invL = 1.0f / L;
    float* op = out + ((size_t)b * T_SEQ + it * 64 + row) * H_DIM + cg;
#pragma unroll
    for (int g = 0; g < 8; ++g) {
        float4 v;
        v.x = acc[g * 4 + 0] * invL;
        v.y = acc[g * 4 + 1] * invL;
        v.z = acc[g * 4 + 2] * invL;
        v.w = acc[g * 4 + 3] * invL;
        *reinterpret_cast<float4*>(op + g * 4) = v;
    }
}

// ---------------------------------------------------------------------------
extern "C" void kernel_launch(void* const* d_in, const int* in_sizes, int n_in,
                              void* d_out, int out_size, void* d_ws, size_t ws_size,
                              hipStream_t stream) {
    const float* x  = (const float*)d_in[0];
    const float* Wk = (const float*)d_in[1];
    const float* Wq = (const float*)d_in[2];
    const float* Wv = (const float*)d_in[3];

    ushort* kqv    = (ushort*)d_ws;
    ushort* wt     = kqv + (size_t)3 * M_ROWS * H_DIM;
    ushort* partO  = wt + (size_t)3 * H_DIM * C_EMB;
    float*  partML = (float*)(partO + (size_t)1024 * 64 * 128);

    transpose_w<<<dim3(64, 3), 256, 0, stream>>>(Wk, Wq, Wv, wt);
    qkv_gemm<<<dim3(128, 2), 512, 0, stream>>>(x, wt, kqv);
    flash_chunk<<<dim3(64 * SPLIT, NBATCH), 256, 0, stream>>>(kqv, partO, partML);
    combine<<<dim3(64, NBATCH), 256, 0, stream>>>(partO, partML, (float*)d_out);
}